// Round 1
// baseline (686.777 us; speedup 1.0000x reference)
//
#include <hip/hip_runtime.h>

#define N_INST 100
#define HW_PIX 819200
#define NPAIR (N_INST * N_INST)

struct alignas(16) Ent { int p; int ab; float ra; float rb; };

// K0: argsort(cls_prob) descending (f32, distinct w.p. 1; tie-break by larger
// original index first == jnp stable-ascending reversed). Also zeroes the
// small accumulators (nc/masksum/paircnt) so no hipMemsetAsync is needed.
__global__ __launch_bounds__(128) void k0_sort(
    const float* __restrict__ cls_prob,
    const int* __restrict__ cls_idx,
    int* __restrict__ order,
    int* __restrict__ cls_sorted,
    float* __restrict__ out_order,
    unsigned int* __restrict__ nc,
    unsigned int* __restrict__ masksum,
    unsigned int* __restrict__ paircnt) {
  int t = threadIdx.x;
  // zero accumulators (ws is poisoned 0xAA by the harness)
  if (t == 0) *nc = 0u;
  for (int i = t; i < N_INST; i += 128) masksum[i] = 0u;
  for (int i = t; i < NPAIR; i += 128) paircnt[i] = 0u;

  __shared__ float v[N_INST];
  __shared__ int ordl[N_INST];
  if (t < N_INST) v[t] = cls_prob[t];
  __syncthreads();
  if (t < N_INST) {
    float mv = v[t];
    int r = 0;
    for (int j = 0; j < N_INST; ++j) {
      float vj = v[j];
      r += (vj > mv) || (vj == mv && j > t);
    }
    ordl[r] = t;
  }
  __syncthreads();
  if (t < N_INST) {
    int o = ordl[t];
    order[t] = o;
    cls_sorted[t] = cls_idx[o];
    out_order[t] = (float)o;  // ints <= 99 exact in f32
  }
}

// Bit-exact per-pixel candidate evaluation replicating np semantics:
// max-subtract (m passed in, computed by the identical fmaxf chain),
// sequential precise-expf f32 sum in sorted-row order, top-2 tracking with
// the same comparison structure, true f32 divisions vs 0.4f.
__device__ __forceinline__ void exact_pixel(
    int p, float m,
    const float* __restrict__ mp,
    const int* __restrict__ order,
    unsigned int* __restrict__ masksum,
    unsigned int* __restrict__ paircnt,
    unsigned int* __restrict__ nc,
    Ent* __restrict__ list) {
  float denom = 0.0f, e1 = -1.0f, e2 = -1.0f, r1 = 0.0f, r2 = 0.0f;
  int s1 = 0, s2 = 0;
  for (int k = 0; k < N_INST; ++k) {
    float xv = mp[(size_t)order[k] * HW_PIX + p];
    float e = expf(xv - m);  // precise expf, matches np f32 semantics ~1ulp
    denom += e;              // sequential order 0..99 like np axis-0 reduce
    if (e > e1)      { e2 = e1; s2 = s1; r2 = r1; e1 = e; s1 = k; r1 = xv; }
    else if (e > e2) { e2 = e;  s2 = k;  r2 = xv; }
  }
  bool c1 = (e1 / denom) >= 0.4f;  // e1 == 1.0f always (argmax term)
  bool c2 = (e2 / denom) >= 0.4f;  // c2 implies c1
  if (c1) {
    int a = s1, b = 255;
    float ra = r1, rb = 0.0f;
    atomicAdd(&masksum[s1], 1u);
    if (c2) {
      atomicAdd(&masksum[s2], 1u);
      if (s2 < s1) { a = s2; ra = r2; b = s1; rb = r1; }
      else         { b = s2; rb = r2; }
      atomicAdd(&paircnt[a * N_INST + b], 1u);
    }
    unsigned idx = atomicAdd(nc, 1u);
    Ent e; e.p = p; e.ab = a | (b << 8); e.ra = ra; e.rb = rb;
    list[idx] = e;
  }
}

// K1: fused (a) zero-fill of the whole kept_masks output, (b) online-softmax
// fast filter, (c) exact fallback for possible candidates.
// Fast path per pixel: running max m (identical fmaxf chain => exact max) and
// online-rescaled denom with __expf. Candidate condition is denom<=2.5
// (since e1==1.0f exactly); fast denom rel-err <~1e-4, guard band 2.51
// (4e-3 rel) => every pixel that could be a candidate under exact math
// provably enters the exact path. ~1e-4 of pixels fall back => negligible.
__global__ __launch_bounds__(256) void k1_cand(
    const float* __restrict__ mp,
    const int* __restrict__ order,
    unsigned int* __restrict__ masksum,
    unsigned int* __restrict__ paircnt,
    unsigned int* __restrict__ nc,
    Ent* __restrict__ list,
    float* __restrict__ out_masks) {
  const int p0 = (blockIdx.x * 256 + threadIdx.x) * 4;
  float4 mx = make_float4(-INFINITY, -INFINITY, -INFINITY, -INFINITY);
  float4 dn = make_float4(0.0f, 0.0f, 0.0f, 0.0f);
  const float4 z = make_float4(0.0f, 0.0f, 0.0f, 0.0f);
#pragma unroll
  for (int k = 0; k < N_INST; ++k) {
    const float4 x = *reinterpret_cast<const float4*>(
        &mp[(size_t)order[k] * HW_PIX + p0]);
    // fused output zeroing: plane k of kept_masks (disjoint buffer, no alias)
    *reinterpret_cast<float4*>(&out_masks[(size_t)k * HW_PIX + p0]) = z;
    float nm;
    nm = fmaxf(mx.x, x.x); dn.x = dn.x * __expf(mx.x - nm) + __expf(x.x - nm); mx.x = nm;
    nm = fmaxf(mx.y, x.y); dn.y = dn.y * __expf(mx.y - nm) + __expf(x.y - nm); mx.y = nm;
    nm = fmaxf(mx.z, x.z); dn.z = dn.z * __expf(mx.z - nm) + __expf(x.z - nm); mx.z = nm;
    nm = fmaxf(mx.w, x.w); dn.w = dn.w * __expf(mx.w - nm) + __expf(x.w - nm); mx.w = nm;
  }
  const float GUARD = 2.51f;  // exact threshold 2.5; fast err <=~1e-4 rel
  bool any = (dn.x <= GUARD) | (dn.y <= GUARD) | (dn.z <= GUARD) | (dn.w <= GUARD);
  if (__builtin_expect(any, 0)) {
    if (dn.x <= GUARD) exact_pixel(p0 + 0, mx.x, mp, order, masksum, paircnt, nc, list);
    if (dn.y <= GUARD) exact_pixel(p0 + 1, mx.y, mp, order, masksum, paircnt, nc, list);
    if (dn.z <= GUARD) exact_pixel(p0 + 2, mx.z, mp, order, masksum, paircnt, nc, list);
    if (dn.w <= GUARD) exact_pixel(p0 + 3, mx.w, mp, order, masksum, paircnt, nc, list);
  }
}

// K2: sequential greedy keep, one block. overlap_s = sum over earlier kept
// same-class j of paircnt[j][s] (valid because a pixel has <=2 candidates,
// so mimg[c] at a pixel is set iff the pixel's other candidate was kept).
__global__ __launch_bounds__(256) void k2_keep(
    const unsigned int* __restrict__ paircnt,
    const unsigned int* __restrict__ masksum,
    const int* __restrict__ cls_sorted,
    unsigned long long* __restrict__ keepmask,
    float* __restrict__ out_keep) {
  __shared__ unsigned int pl[NPAIR];
  __shared__ unsigned int ms[N_INST];
  __shared__ int cl[N_INST];
  for (int i = threadIdx.x; i < NPAIR; i += 256) pl[i] = paircnt[i];
  if (threadIdx.x < N_INST) {
    ms[threadIdx.x] = masksum[threadIdx.x];
    cl[threadIdx.x] = cls_sorted[threadIdx.x];
  }
  __syncthreads();
  if (threadIdx.x < 64) {
    int l = threadIdx.x;
    int j2 = l + 64;
    int cA = cl[l];
    int cB = (j2 < N_INST) ? cl[j2] : -1;
    bool kA = false, kB = false;
    unsigned long long km0 = 0, km1 = 0;
    for (int s = 0; s < N_INST; ++s) {
      int cs = cl[s];
      unsigned int ov = 0;
      if (l < s && kA && cA == cs) ov += pl[l * N_INST + s];
      if (j2 < s && kB && cB == cs) ov += pl[j2 * N_INST + s];
#pragma unroll
      for (int off = 32; off >= 1; off >>= 1) ov += __shfl_xor((int)ov, off);
      unsigned int m_s = ms[s];
      float overlap = (float)ov / fmaxf((float)m_s, 1.0f);
      bool keep = (m_s > 0u) && (m_s < (unsigned)HW_PIX) && (overlap <= 0.03f);
      if (keep) { if (s < 64) km0 |= 1ull << s; else km1 |= 1ull << (s - 64); }
      if (s == l)  kA = keep;
      if (s == j2) kB = keep;
    }
    if (l == 0) { keepmask[0] = km0; keepmask[1] = km1; }
    out_keep[l] = kA ? 1.0f : 0.0f;
    if (j2 < N_INST) out_keep[j2] = kB ? 1.0f : 0.0f;
  }
}

// K3: sparse scatter of kept candidate pixels onto the zeroed output
// (zeros written by k1; k3 runs strictly after => no race).
__global__ __launch_bounds__(256) void k3_scatter(
    const unsigned int* __restrict__ nc,
    const Ent* __restrict__ list,
    const unsigned long long* __restrict__ keepmask,
    float* __restrict__ out_masks) {
  unsigned long long km0 = keepmask[0], km1 = keepmask[1];
  unsigned n = *nc;
  for (unsigned i = blockIdx.x * 256 + threadIdx.x; i < n; i += gridDim.x * 256) {
    Ent e = list[i];
    int a = e.ab & 0xFF;
    int b = (e.ab >> 8) & 0xFF;
    bool ka = (a < 64) ? (((km0 >> a) & 1ull) != 0)
                       : ((a < N_INST) && (((km1 >> (a - 64)) & 1ull) != 0));
    bool kb = (b < 64) ? (((km0 >> b) & 1ull) != 0)
                       : ((b < N_INST) && (((km1 >> (b - 64)) & 1ull) != 0));
    if (ka)      out_masks[(size_t)a * HW_PIX + e.p] = e.ra;
    else if (kb) out_masks[(size_t)b * HW_PIX + e.p] = e.rb;
  }
}

extern "C" void kernel_launch(void* const* d_in, const int* in_sizes, int n_in,
                              void* d_out, int out_size, void* d_ws, size_t ws_size,
                              hipStream_t stream) {
  const float* cls_prob = (const float*)d_in[0];
  const float* mp       = (const float*)d_in[1];
  const int*   cls_idx  = (const int*)d_in[2];
  float* out = (float*)d_out;

  char* ws = (char*)d_ws;
  int* order                   = (int*)(ws + 0);       // 400 B
  int* cls_sorted              = (int*)(ws + 400);     // 400 B
  unsigned long long* keepmask = (unsigned long long*)(ws + 800);  // 16 B
  unsigned int* nc             = (unsigned int*)(ws + 1024);       // 4 B
  unsigned int* masksum        = (unsigned int*)(ws + 2048);       // 400 B
  unsigned int* paircnt        = (unsigned int*)(ws + 4096);       // 40 KB
  Ent* list                    = (Ent*)(ws + 65536);   // up to 13.1 MB worst case

  // output layout (f32): keep[100] | kept_masks[100*HW] | order[100]
  float* out_keep  = out;
  float* out_masks = out + N_INST;
  float* out_order = out + N_INST + (size_t)N_INST * HW_PIX;

  // No memsets: k0 zeroes the accumulators, k1 zero-fills kept_masks.
  k0_sort<<<1, 128, 0, stream>>>(cls_prob, cls_idx, order, cls_sorted, out_order,
                                 nc, masksum, paircnt);
  k1_cand<<<HW_PIX / 1024, 256, 0, stream>>>(mp, order, masksum, paircnt, nc,
                                             list, out_masks);
  k2_keep<<<1, 256, 0, stream>>>(paircnt, masksum, cls_sorted, keepmask, out_keep);
  k3_scatter<<<128, 256, 0, stream>>>(nc, list, keepmask, out_masks);
}

// Round 3
// 653.947 us; speedup vs baseline: 1.0502x; 1.0502x over previous
//
#include <hip/hip_runtime.h>

#define N_INST 100
#define HW_PIX 819200
#define NPAIR (N_INST * N_INST)

struct alignas(16) Ent { int p; int ab; float ra; float rb; };

// K0: argsort(cls_prob) descending (f32, distinct w.p. 1; tie-break by larger
// original index first == jnp stable-ascending reversed). Also zeroes the
// small accumulators (nc/masksum/paircnt) so no hipMemsetAsync is needed.
__global__ __launch_bounds__(128) void k0_sort(
    const float* __restrict__ cls_prob,
    const int* __restrict__ cls_idx,
    int* __restrict__ order,
    int* __restrict__ cls_sorted,
    float* __restrict__ out_order,
    unsigned int* __restrict__ nc,
    unsigned int* __restrict__ masksum,
    unsigned int* __restrict__ paircnt) {
  int t = threadIdx.x;
  // zero accumulators (ws is poisoned 0xAA by the harness)
  if (t == 0) *nc = 0u;
  for (int i = t; i < N_INST; i += 128) masksum[i] = 0u;
  for (int i = t; i < NPAIR; i += 128) paircnt[i] = 0u;

  __shared__ float v[N_INST];
  __shared__ int ordl[N_INST];
  if (t < N_INST) v[t] = cls_prob[t];
  __syncthreads();
  if (t < N_INST) {
    float mv = v[t];
    int r = 0;
    for (int j = 0; j < N_INST; ++j) {
      float vj = v[j];
      r += (vj > mv) || (vj == mv && j > t);
    }
    ordl[r] = t;
  }
  __syncthreads();
  if (t < N_INST) {
    int o = ordl[t];
    order[t] = o;
    cls_sorted[t] = cls_idx[o];
    out_order[t] = (float)o;  // ints <= 99 exact in f32
  }
}

// Bit-exact per-pixel candidate evaluation replicating np semantics:
// max-subtract (m passed in == exact fmaxf chain result, order-independent),
// sequential precise-expf f32 sum in sorted-row order, top-2 tracking with
// the same comparison structure, true f32 divisions vs 0.4f.
__device__ __forceinline__ void exact_pixel(
    int p, float m,
    const float* __restrict__ mp,
    const int* __restrict__ order,
    unsigned int* __restrict__ masksum,
    unsigned int* __restrict__ paircnt,
    unsigned int* __restrict__ nc,
    Ent* __restrict__ list) {
  float denom = 0.0f, e1 = -1.0f, e2 = -1.0f, r1 = 0.0f, r2 = 0.0f;
  int s1 = 0, s2 = 0;
  for (int k = 0; k < N_INST; ++k) {
    float xv = mp[(size_t)order[k] * HW_PIX + p];
    float e = expf(xv - m);  // precise expf, matches np f32 semantics ~1ulp
    denom += e;              // sequential order 0..99 like np axis-0 reduce
    if (e > e1)      { e2 = e1; s2 = s1; r2 = r1; e1 = e; s1 = k; r1 = xv; }
    else if (e > e2) { e2 = e;  s2 = k;  r2 = xv; }
  }
  bool c1 = (e1 / denom) >= 0.4f;  // e1 == 1.0f always (argmax term)
  bool c2 = (e2 / denom) >= 0.4f;  // c2 implies c1
  if (c1) {
    int a = s1, b = 255;
    float ra = r1, rb = 0.0f;
    atomicAdd(&masksum[s1], 1u);
    if (c2) {
      atomicAdd(&masksum[s2], 1u);
      if (s2 < s1) { a = s2; ra = r2; b = s1; rb = r1; }
      else         { b = s2; rb = r2; }
      atomicAdd(&paircnt[a * N_INST + b], 1u);
    }
    unsigned idx = atomicAdd(nc, 1u);
    Ent e; e.p = p; e.ab = a | (b << 8); e.ra = ra; e.rb = rb;
    list[idx] = e;
  }
}

// K1: read-only fast filter with guaranteed MLP.
// Per pixel: m = max(x_k) (exact fmax chain, order-independent) and
// S = sum __expf(x_k) (no overflow for |x|<=60; all terms positive).
// denom_est = S * __expf(-m) approximates denom = sum exp(x_k - m) to
// ~1e-5 rel. Candidate condition (top softmax >= 0.4, and e1 == 1.0f
// exactly) is denom <= 2.5, so: skip pixel iff denom_est > 2.51 AND
// |m| <= 60 AND denom_est finite. Everything else -> bit-exact fallback.
// Loads are batched 10 planes deep into registers (static indices) so each
// wave keeps >=10 x 512B loads in flight -> BW-bound, not latency-bound.
__global__ __launch_bounds__(256) void k1_cand(
    const float* __restrict__ mp,
    const int* __restrict__ order,
    unsigned int* __restrict__ masksum,
    unsigned int* __restrict__ paircnt,
    unsigned int* __restrict__ nc,
    Ent* __restrict__ list) {
  __shared__ int ord_s[N_INST];
  if (threadIdx.x < N_INST) ord_s[threadIdx.x] = order[threadIdx.x];
  __syncthreads();
  const int p0 = (blockIdx.x * 256 + threadIdx.x) * 2;
  float mxa = -INFINITY, mxb = -INFINITY;
  float sa = 0.0f, sb = 0.0f;
#pragma unroll
  for (int b = 0; b < 10; ++b) {
    float2 x[10];
#pragma unroll
    for (int j = 0; j < 10; ++j)
      x[j] = *reinterpret_cast<const float2*>(
          &mp[(size_t)ord_s[b * 10 + j] * HW_PIX + p0]);
#pragma unroll
    for (int j = 0; j < 10; ++j) {
      sa += __expf(x[j].x); mxa = fmaxf(mxa, x[j].x);
      sb += __expf(x[j].y); mxb = fmaxf(mxb, x[j].y);
    }
  }
  float da = sa * __expf(-mxa);
  float db = sb * __expf(-mxb);
  const float GUARD = 2.51f;  // exact threshold 2.5; est rel err ~1e-5
  bool ea = !(da > GUARD) || (fabsf(mxa) > 60.0f);  // NaN/inf -> exact path
  bool eb = !(db > GUARD) || (fabsf(mxb) > 60.0f);
  if (__builtin_expect(ea || eb, 0)) {
    if (ea) exact_pixel(p0 + 0, mxa, mp, order, masksum, paircnt, nc, list);
    if (eb) exact_pixel(p0 + 1, mxb, mp, order, masksum, paircnt, nc, list);
  }
}

// K2: sequential greedy keep, one block. overlap_s = sum over earlier kept
// same-class j of paircnt[j][s] (valid because a pixel has <=2 candidates,
// so mimg[c] at a pixel is set iff the pixel's other candidate was kept).
__global__ __launch_bounds__(256) void k2_keep(
    const unsigned int* __restrict__ paircnt,
    const unsigned int* __restrict__ masksum,
    const int* __restrict__ cls_sorted,
    unsigned long long* __restrict__ keepmask,
    float* __restrict__ out_keep) {
  __shared__ unsigned int pl[NPAIR];
  __shared__ unsigned int ms[N_INST];
  __shared__ int cl[N_INST];
  for (int i = threadIdx.x; i < NPAIR; i += 256) pl[i] = paircnt[i];
  if (threadIdx.x < N_INST) {
    ms[threadIdx.x] = masksum[threadIdx.x];
    cl[threadIdx.x] = cls_sorted[threadIdx.x];
  }
  __syncthreads();
  if (threadIdx.x < 64) {
    int l = threadIdx.x;
    int j2 = l + 64;
    int cA = cl[l];
    int cB = (j2 < N_INST) ? cl[j2] : -1;
    bool kA = false, kB = false;
    unsigned long long km0 = 0, km1 = 0;
    for (int s = 0; s < N_INST; ++s) {
      int cs = cl[s];
      unsigned int ov = 0;
      if (l < s && kA && cA == cs) ov += pl[l * N_INST + s];
      if (j2 < s && kB && cB == cs) ov += pl[j2 * N_INST + s];
#pragma unroll
      for (int off = 32; off >= 1; off >>= 1) ov += __shfl_xor((int)ov, off);
      unsigned int m_s = ms[s];
      float overlap = (float)ov / fmaxf((float)m_s, 1.0f);
      bool keep = (m_s > 0u) && (m_s < (unsigned)HW_PIX) && (overlap <= 0.03f);
      if (keep) { if (s < 64) km0 |= 1ull << s; else km1 |= 1ull << (s - 64); }
      if (s == l)  kA = keep;
      if (s == j2) kB = keep;
    }
    if (l == 0) { keepmask[0] = km0; keepmask[1] = km1; }
    out_keep[l] = kA ? 1.0f : 0.0f;
    if (j2 < N_INST) out_keep[j2] = kB ? 1.0f : 0.0f;
  }
}

// K3: sparse scatter of kept candidate pixels onto the memset-zeroed output.
__global__ __launch_bounds__(256) void k3_scatter(
    const unsigned int* __restrict__ nc,
    const Ent* __restrict__ list,
    const unsigned long long* __restrict__ keepmask,
    float* __restrict__ out_masks) {
  unsigned long long km0 = keepmask[0], km1 = keepmask[1];
  unsigned n = *nc;
  for (unsigned i = blockIdx.x * 256 + threadIdx.x; i < n; i += gridDim.x * 256) {
    Ent e = list[i];
    int a = e.ab & 0xFF;
    int b = (e.ab >> 8) & 0xFF;
    bool ka = (a < 64) ? (((km0 >> a) & 1ull) != 0)
                       : ((a < N_INST) && (((km1 >> (a - 64)) & 1ull) != 0));
    bool kb = (b < 64) ? (((km0 >> b) & 1ull) != 0)
                       : ((b < N_INST) && (((km1 >> (b - 64)) & 1ull) != 0));
    if (ka)      out_masks[(size_t)a * HW_PIX + e.p] = e.ra;
    else if (kb) out_masks[(size_t)b * HW_PIX + e.p] = e.rb;
  }
}

extern "C" void kernel_launch(void* const* d_in, const int* in_sizes, int n_in,
                              void* d_out, int out_size, void* d_ws, size_t ws_size,
                              hipStream_t stream) {
  const float* cls_prob = (const float*)d_in[0];
  const float* mp       = (const float*)d_in[1];
  const int*   cls_idx  = (const int*)d_in[2];
  float* out = (float*)d_out;

  char* ws = (char*)d_ws;
  int* order                   = (int*)(ws + 0);       // 400 B
  int* cls_sorted              = (int*)(ws + 400);     // 400 B
  unsigned long long* keepmask = (unsigned long long*)(ws + 800);  // 16 B
  unsigned int* nc             = (unsigned int*)(ws + 1024);       // 4 B
  unsigned int* masksum        = (unsigned int*)(ws + 2048);       // 400 B
  unsigned int* paircnt        = (unsigned int*)(ws + 4096);       // 40 KB
  Ent* list                    = (Ent*)(ws + 65536);   // up to 13.1 MB worst case

  // output layout (f32): keep[100] | kept_masks[100*HW] | order[100]
  float* out_keep  = out;
  float* out_masks = out + N_INST;
  float* out_order = out + N_INST + (size_t)N_INST * HW_PIX;

  // Output zero-fill as a plain fill (measured 6.35 TB/s); k0 zeroes the
  // small accumulators. k1 is a pure read-streaming kernel.
  hipMemsetAsync(out_masks, 0, (size_t)N_INST * HW_PIX * sizeof(float), stream);
  k0_sort<<<1, 128, 0, stream>>>(cls_prob, cls_idx, order, cls_sorted, out_order,
                                 nc, masksum, paircnt);
  k1_cand<<<HW_PIX / 512, 256, 0, stream>>>(mp, order, masksum, paircnt, nc, list);
  k2_keep<<<1, 256, 0, stream>>>(paircnt, masksum, cls_sorted, keepmask, out_keep);
  k3_scatter<<<128, 256, 0, stream>>>(nc, list, keepmask, out_masks);
}